// Round 1
// baseline (169.580 us; speedup 1.0000x reference)
//
#include <hip/hip_runtime.h>
#include <hip/hip_bf16.h>

// Problem constants
#define NH   8
#define NS   256
#define NT   1024
#define ND   64
#define NB   128      // SZ_B * NH

typedef __attribute__((ext_vector_type(4))) float f32x4;
typedef __attribute__((ext_vector_type(8))) short short8;

__device__ __forceinline__ short f2bf(float f) {
    union { float f; unsigned u; } v; v.f = f;
    unsigned r = v.u + 0x7FFFu + ((v.u >> 16) & 1u);   // RNE
    return (short)(r >> 16);
}

// out[b,t,s] = q[b,t,:] . ( s <= t/4 ? e1[h, 255-(t/4-s), :] : e2[h, s-t/4, :] ),  h=b%8
// One block per (h, a=t/4): 64 q-rows (16 b_outer x 4 dt) x 256 s-cols, K=64.
__global__ __launch_bounds__(256) void srel_kernel(
    const float* __restrict__ q, const float* __restrict__ e1,
    const float* __restrict__ e2, float* __restrict__ out)
{
    const int h   = blockIdx.x >> 8;    // 0..7
    const int a   = blockIdx.x & 255;   // 0..255
    const int tid = threadIdx.x;

    // +8 pad (stride 72 bf16 = 144 B = 36 banks) -> 2-way bank aliasing (free)
    __shared__ __align__(16) unsigned short lA[64 * 72];   // q tile, row m, k-major
    __shared__ __align__(16) unsigned short lB[NS * 72];   // Ecomb,  row s, k-major

    // ---- stage q tile: m = b_outer*4 + dt; 4 threads per row, 16 floats each ----
    {
        const int m    = tid >> 2;          // 0..63
        const int part = tid & 3;           // float offset part*16
        const int b    = (m >> 2) * NH + h;
        const int t    = a * 4 + (m & 3);
        const float4* src = (const float4*)(q + ((size_t)b * NT + t) * ND + part * 16);
        unsigned short* dst = lA + m * 72 + part * 16;
        float4 v0 = src[0], v1 = src[1], v2 = src[2], v3 = src[3];
        short8 p0, p1;
        p0[0]=f2bf(v0.x); p0[1]=f2bf(v0.y); p0[2]=f2bf(v0.z); p0[3]=f2bf(v0.w);
        p0[4]=f2bf(v1.x); p0[5]=f2bf(v1.y); p0[6]=f2bf(v1.z); p0[7]=f2bf(v1.w);
        p1[0]=f2bf(v2.x); p1[1]=f2bf(v2.y); p1[2]=f2bf(v2.z); p1[3]=f2bf(v2.w);
        p1[4]=f2bf(v3.x); p1[5]=f2bf(v3.y); p1[6]=f2bf(v3.z); p1[7]=f2bf(v3.w);
        *(short8*)dst       = p0;
        *(short8*)(dst + 8) = p1;
    }

    // ---- stage Ecomb: row s -> e1[h,255-a+s] if s<=a else e2[h,s-a] ----
    #pragma unroll
    for (int p = 0; p < 4; ++p) {
        const int s    = p * 64 + (tid >> 2);   // 0..255
        const int part = tid & 3;
        const float* base = (s <= a)
            ? (e1 + ((size_t)(h * NS + (255 - a + s))) * ND)
            : (e2 + ((size_t)(h * NS + (s - a)))       * ND);
        const float4* src = (const float4*)(base + part * 16);
        unsigned short* dst = lB + s * 72 + part * 16;
        float4 v0 = src[0], v1 = src[1], v2 = src[2], v3 = src[3];
        short8 p0, p1;
        p0[0]=f2bf(v0.x); p0[1]=f2bf(v0.y); p0[2]=f2bf(v0.z); p0[3]=f2bf(v0.w);
        p0[4]=f2bf(v1.x); p0[5]=f2bf(v1.y); p0[6]=f2bf(v1.z); p0[7]=f2bf(v1.w);
        p1[0]=f2bf(v2.x); p1[1]=f2bf(v2.y); p1[2]=f2bf(v2.z); p1[3]=f2bf(v2.w);
        p1[4]=f2bf(v3.x); p1[5]=f2bf(v3.y); p1[6]=f2bf(v3.z); p1[7]=f2bf(v3.w);
        *(short8*)dst       = p0;
        *(short8*)(dst + 8) = p1;
    }

    __syncthreads();

    // ---- MFMA: wave w handles cols [w*64, w*64+64), all 64 rows ----
    const int wave = tid >> 6;
    const int lane = tid & 63;
    const int lrow = lane & 15;   // A row-in-tile / B col-in-tile
    const int quad = lane >> 4;   // k sub-block

    f32x4 acc[4][4] = {};
    #pragma unroll
    for (int kk = 0; kk < 64; kk += 32) {
        short8 afr[4], bfr[4];
        #pragma unroll
        for (int tm = 0; tm < 4; ++tm)
            afr[tm] = *(const short8*)(lA + (tm * 16 + lrow) * 72 + kk + quad * 8);
        #pragma unroll
        for (int tn = 0; tn < 4; ++tn)
            bfr[tn] = *(const short8*)(lB + (wave * 64 + tn * 16 + lrow) * 72 + kk + quad * 8);
        #pragma unroll
        for (int tm = 0; tm < 4; ++tm)
            #pragma unroll
            for (int tn = 0; tn < 4; ++tn)
                acc[tm][tn] = __builtin_amdgcn_mfma_f32_16x16x32_bf16(
                    afr[tm], bfr[tn], acc[tm][tn], 0, 0, 0);
    }

    // ---- epilogue: C/D layout col=lane&15, row=quad*4+reg ----
    #pragma unroll
    for (int tm = 0; tm < 4; ++tm) {
        #pragma unroll
        for (int r = 0; r < 4; ++r) {
            const int m = tm * 16 + quad * 4 + r;
            const int b = (m >> 2) * NH + h;
            const int t = a * 4 + (m & 3);
            float* orow = out + ((size_t)b * NT + t) * NS + wave * 64 + lrow;
            #pragma unroll
            for (int tn = 0; tn < 4; ++tn)
                orow[tn * 16] = acc[tm][tn][r];
        }
    }
}

extern "C" void kernel_launch(void* const* d_in, const int* in_sizes, int n_in,
                              void* d_out, int out_size, void* d_ws, size_t ws_size,
                              hipStream_t stream) {
    (void)in_sizes; (void)n_in; (void)d_ws; (void)ws_size; (void)out_size;
    const float* q  = (const float*)d_in[0];
    const float* e1 = (const float*)d_in[1];
    const float* e2 = (const float*)d_in[2];
    float* out = (float*)d_out;
    srel_kernel<<<dim3(NH * NS), dim3(256), 0, stream>>>(q, e1, e2, out);
}

// Round 2
// 166.591 us; speedup vs baseline: 1.0179x; 1.0179x over previous
//
#include <hip/hip_runtime.h>
#include <hip/hip_bf16.h>

#define NH   8
#define NS   256
#define NT   1024
#define ND   64
#define NB   128      // SZ_B * NH
#define ESZ  (NH * NS * ND)   // 131072 elements per e-table

typedef __attribute__((ext_vector_type(4))) float f32x4;
typedef __attribute__((ext_vector_type(8))) short short8;

__device__ __forceinline__ short f2bf(float f) {
    union { float f; unsigned u; } v; v.f = f;
    unsigned r = v.u + 0x7FFFu + ((v.u >> 16) & 1u);   // RNE
    return (short)(r >> 16);
}

// One-shot: convert e1,e2 (f32) -> bf16 table in ws. eb[0:ESZ)=e1, [ESZ:2*ESZ)=e2.
__global__ __launch_bounds__(256) void cvt_e_kernel(
    const float* __restrict__ e1, const float* __restrict__ e2,
    unsigned short* __restrict__ eb)
{
    const int i = (blockIdx.x * 256 + threadIdx.x) * 8;   // 8 elems/thread
    const float* src = (i < ESZ) ? (e1 + i) : (e2 + (i - ESZ));
    float4 v0 = ((const float4*)src)[0];
    float4 v1 = ((const float4*)src)[1];
    short8 p;
    p[0]=f2bf(v0.x); p[1]=f2bf(v0.y); p[2]=f2bf(v0.z); p[3]=f2bf(v0.w);
    p[4]=f2bf(v1.x); p[5]=f2bf(v1.y); p[6]=f2bf(v1.z); p[7]=f2bf(v1.w);
    *(short8*)(eb + i) = p;
}

// out[b,t,s] = q[b,t,:] . ( s <= t/4 ? e1[h, 255-(t/4-s), :] : e2[h, s-t/4, :] ),  h=b%8
// Block per (h, a=t/4): 64 q-rows x 256 s-cols GEMM, K=64, bf16 MFMA.
// LDS: lA 8 KB + lB 32 KB = 40960 B -> exactly 4 blocks/CU.
// Layout: 64-short rows, 16B chunk c of row r stored at phys chunk (c ^ (r&7))
// -> conflict-free b128 reads AND compatible with global_load_lds lane mapping.
__global__ __launch_bounds__(256, 4) void srel_kernel(
    const float* __restrict__ q, const unsigned short* __restrict__ eb,
    float* __restrict__ out)
{
    const int h   = blockIdx.x >> 8;
    const int a   = blockIdx.x & 255;
    const int tid = threadIdx.x;
    const int wave = tid >> 6;
    const int lane = tid & 63;

    __shared__ __align__(16) char smem[64*64*2 + NS*64*2];   // 40960 B
    unsigned short* lA = (unsigned short*)smem;               // 64 rows x 64 shorts
    unsigned short* lB = (unsigned short*)(smem + 64*64*2);   // 256 rows x 64 shorts
    float* fbuf = (float*)smem;                               // epilogue reuse (33280 B)

    // ---- stage B: async global->LDS, bf16 source, XOR swizzle baked into src ----
    {
        const unsigned short* eb1 = eb;
        const unsigned short* eb2 = eb + ESZ;
        const int srow = lane >> 3;          // row within 8-row group
        const int physc = lane & 7;          // phys chunk this lane fills
        #pragma unroll
        for (int rnd = 0; rnd < 8; ++rnd) {
            const int s = rnd * 32 + wave * 8 + srow;
            const int j = physc ^ (s & 7);   // logical chunk to fetch
            const unsigned short* src = (s <= a)
                ? (eb1 + (h * NS + 255 - a + s) * ND + j * 8)
                : (eb2 + (h * NS + s - a)       * ND + j * 8);
            __builtin_amdgcn_global_load_lds(
                (const __attribute__((address_space(1))) void*)src,
                (__attribute__((address_space(3))) void*)(lB + (rnd * 32 + wave * 8) * 64),
                16, 0, 0);
        }
    }

    // ---- stage A: q tile (f32 -> bf16 in VALU), swizzled chunks ----
    {
        const int m    = tid >> 2;
        const int part = tid & 3;
        const int b    = (m >> 2) * NH + h;
        const int t    = a * 4 + (m & 3);
        const float4* src = (const float4*)(q + ((size_t)b * NT + t) * ND + part * 16);
        float4 v0 = src[0], v1 = src[1], v2 = src[2], v3 = src[3];
        short8 p0, p1;
        p0[0]=f2bf(v0.x); p0[1]=f2bf(v0.y); p0[2]=f2bf(v0.z); p0[3]=f2bf(v0.w);
        p0[4]=f2bf(v1.x); p0[5]=f2bf(v1.y); p0[6]=f2bf(v1.z); p0[7]=f2bf(v1.w);
        p1[0]=f2bf(v2.x); p1[1]=f2bf(v2.y); p1[2]=f2bf(v2.z); p1[3]=f2bf(v2.w);
        p1[4]=f2bf(v3.x); p1[5]=f2bf(v3.y); p1[6]=f2bf(v3.z); p1[7]=f2bf(v3.w);
        const int sw = m & 7;
        *(short8*)(lA + m * 64 + (((2*part)   ^ sw) * 8)) = p0;
        *(short8*)(lA + m * 64 + (((2*part+1) ^ sw) * 8)) = p1;
    }

    __syncthreads();

    // ---- MFMA: wave w -> cols [w*64, w*64+64), 16 tiles of 16x16, K=64 ----
    const int lrow = lane & 15;
    const int quad = lane >> 4;
    f32x4 acc[4][4] = {};
    #pragma unroll
    for (int kk2 = 0; kk2 < 2; ++kk2) {
        const int swz = ((4 * kk2 + quad) ^ (lrow & 7)) * 8;
        short8 afr[4], bfr[4];
        #pragma unroll
        for (int tm = 0; tm < 4; ++tm)
            afr[tm] = *(const short8*)(lA + (tm * 16 + lrow) * 64 + swz);
        #pragma unroll
        for (int tn = 0; tn < 4; ++tn)
            bfr[tn] = *(const short8*)(lB + (wave * 64 + tn * 16 + lrow) * 64 + swz);
        #pragma unroll
        for (int tm = 0; tm < 4; ++tm)
            #pragma unroll
            for (int tn = 0; tn < 4; ++tn)
                acc[tm][tn] = __builtin_amdgcn_mfma_f32_16x16x32_bf16(
                    afr[tm], bfr[tn], acc[tm][tn], 0, 0, 0);
    }

    // ---- epilogue: bounce through LDS, store full 1 KB rows as dwordx4 ----
    // C/D layout: col = lane&15, row-in-tile = quad*4 + reg.
    #pragma unroll
    for (int c = 0; c < 2; ++c) {
        __syncthreads();   // protect smem reuse (chunk0: vs frag reads; chunk1: vs chunk0 reads)
        #pragma unroll
        for (int tmh = 0; tmh < 2; ++tmh) {
            const int tm = c * 2 + tmh;
            #pragma unroll
            for (int r = 0; r < 4; ++r) {
                const int rl = tmh * 16 + quad * 4 + r;   // 0..31
                #pragma unroll
                for (int tn = 0; tn < 4; ++tn)
                    fbuf[rl * 260 + wave * 64 + tn * 16 + lrow] = acc[tm][tn][r];
            }
        }
        __syncthreads();
        #pragma unroll
        for (int i = 0; i < 8; ++i) {
            const int rl = i * 4 + wave;                  // 0..31
            const int m  = c * 32 + rl;
            const int b  = (m >> 2) * NH + h;
            const int t  = a * 4 + (m & 3);
            f32x4 v = *(const f32x4*)(fbuf + rl * 260 + lane * 4);
            *(f32x4*)(out + ((size_t)b * NT + t) * NS + lane * 4) = v;
        }
    }
}

extern "C" void kernel_launch(void* const* d_in, const int* in_sizes, int n_in,
                              void* d_out, int out_size, void* d_ws, size_t ws_size,
                              hipStream_t stream) {
    (void)in_sizes; (void)n_in; (void)ws_size; (void)out_size;
    const float* q  = (const float*)d_in[0];
    const float* e1 = (const float*)d_in[1];
    const float* e2 = (const float*)d_in[2];
    float* out = (float*)d_out;
    unsigned short* eb = (unsigned short*)d_ws;

    cvt_e_kernel<<<dim3(2 * ESZ / (256 * 8)), dim3(256), 0, stream>>>(e1, e2, eb);
    srel_kernel<<<dim3(NH * NS), dim3(256), 0, stream>>>(q, eb, out);
}